// Round 7
// baseline (4663.595 us; speedup 1.0000x reference)
//
#include <hip/hip_runtime.h>

// SentenceEncodingRNN2: 2-layer BiLSTM (T=256,B=128,D=300,H=256) + attention pooling.
// Round 16: R11 structure (best: 191us) + flag-based exchange.
//   R12-R15 post-mortem: all lost to R11 (dir-parallelism already existed across
//   blocks). Real exchange cost: agent-scope atomics meet at L3; R11 re-polled
//   2048 dwords/block/pass through that path. Fix: producer stores data ->
//   __syncthreads (vmcnt drain = data acked at coherence point) -> tid0
//   release-stores ONE flag; consumer polls 1 dword/thread (8 flags lane-spread),
//   then bulk-reads once. Ring sentinel memsets (8x16MB) -> flag memsets (8x64KB).
//   proj_gemm2 / attn_gemm / attn_final unchanged.

#define T_ 256
#define B_ 128
#define D_ 300
#define H_ 256
#define G4H 1024   // 4*H
#define H2 512     // 2*H
#define TC 64      // time-chunk length
#define LDK 40     // proj/attn LDS k-stride in bf16 (80 B rows)
#define LDA 264    // lstm A-tile LDS k-stride in bf16 (256+8)

typedef __attribute__((ext_vector_type(8))) short bf16x8;
typedef __attribute__((ext_vector_type(4))) short short4v;
typedef __attribute__((ext_vector_type(4))) float f32x4;

#define MFMA16(a, b, c) __builtin_amdgcn_mfma_f32_16x16x32_bf16(a, b, c, 0, 0, 0)
#define ATOM_ST(p, v) __hip_atomic_store((p), (v), __ATOMIC_RELAXED, __HIP_MEMORY_SCOPE_AGENT)
#define ATOM_LD(p) __hip_atomic_load((p), __ATOMIC_RELAXED, __HIP_MEMORY_SCOPE_AGENT)

// ---------------- helpers ----------------
__device__ __forceinline__ float sigf(float x) { return 1.f / (1.f + __expf(-x)); }
__device__ __forceinline__ float tanhfast(float x) { return 2.f / (1.f + __expf(-2.f * x)) - 1.f; }

__device__ __forceinline__ short hi_bf16(float x) {
  return (short)(__float_as_uint(x) >> 16);
}
__device__ __forceinline__ short lo_bf16(float x) {
  float lo = x - __uint_as_float(__float_as_uint(x) & 0xFFFF0000u);
  return (short)(__float_as_uint(lo) >> 16);
}

__device__ __forceinline__ void split_f4(const float4 v, short* hp, short* lp) {
  short4v h, l;
  h.x = hi_bf16(v.x); l.x = lo_bf16(v.x);
  h.y = hi_bf16(v.y); l.y = lo_bf16(v.y);
  h.z = hi_bf16(v.z); l.z = lo_bf16(v.z);
  h.w = hi_bf16(v.w); l.w = lo_bf16(v.w);
  *(short4v*)hp = h;
  *(short4v*)lp = l;
}

__device__ __forceinline__ void split8(const float4 v0, const float4 v1,
                                       bf16x8* hp, bf16x8* lp) {
  bf16x8 h, l;
  h[0] = hi_bf16(v0.x); l[0] = lo_bf16(v0.x);
  h[1] = hi_bf16(v0.y); l[1] = lo_bf16(v0.y);
  h[2] = hi_bf16(v0.z); l[2] = lo_bf16(v0.z);
  h[3] = hi_bf16(v0.w); l[3] = lo_bf16(v0.w);
  h[4] = hi_bf16(v1.x); l[4] = lo_bf16(v1.x);
  h[5] = hi_bf16(v1.y); l[5] = lo_bf16(v1.y);
  h[6] = hi_bf16(v1.z); l[6] = lo_bf16(v1.z);
  h[7] = hi_bf16(v1.w); l[7] = lo_bf16(v1.w);
  *hp = h; *lp = l;
}

// ---------------- dual-direction projection GEMM, split-bf16 MFMA ----------------
__global__ __launch_bounds__(256, 2) void proj_gemm2(
    const float* __restrict__ X,
    const float* __restrict__ W0, const float* __restrict__ W1,
    const float* __restrict__ b1f, const float* __restrict__ b2f,
    const float* __restrict__ b1r, const float* __restrict__ b2r,
    float* __restrict__ C0, float* __restrict__ C1,
    int N, int K, const int* __restrict__ lengths, int t0)
{
  __shared__ short Xh[128 * LDK], Xl[128 * LDK];
  __shared__ short Wh[128 * LDK], Wl[128 * LDK];
  const int rev = blockIdx.z;
  const float* __restrict__ W = rev ? W1 : W0;
  const float* __restrict__ bias1 = rev ? b1r : b1f;
  const float* __restrict__ bias2 = rev ? b2r : b2f;
  float* __restrict__ C = rev ? C1 : C0;

  const int tid = threadIdx.x;
  const int m0 = blockIdx.y * 128, n0 = blockIdx.x * 128;
  const int s_step = t0 + blockIdx.y;

  const int sr = tid >> 3;
  const int sc = (tid & 7) * 4;
  const float* px[4];
  const float* pw[4];
#pragma unroll
  for (int p = 0; p < 4; p++) {
    const int r = sr + p * 32;          // r == batch index within tile
    int ss = s_step;
    if (rev) {
      int lb = lengths[r]; if (lb < 1) lb = 1;
      ss = (s_step < lb) ? (lb - 1 - s_step) : s_step;
    }
    px[p] = X + (size_t)(ss * 128 + r) * K;
    pw[p] = W + (size_t)(n0 + r) * K;
  }

  const int lane = tid & 63, w = tid >> 6;
  const int mb = (w & 1) * 64, nb = (w >> 1) * 64;
  const int r16 = lane & 15, quad = lane >> 4;

  f32x4 acc[4][4];
#pragma unroll
  for (int i = 0; i < 4; i++)
#pragma unroll
    for (int j = 0; j < 4; j++) acc[i][j] = (f32x4){0.f, 0.f, 0.f, 0.f};

  for (int k0 = 0; k0 < K; k0 += 32) {
    const int gk = k0 + sc;
    const bool kin = (gk < K);          // K % 4 == 0 -> whole float4 in/out
#pragma unroll
    for (int p = 0; p < 4; p++) {
      float4 xv = {0.f, 0.f, 0.f, 0.f}, wv = {0.f, 0.f, 0.f, 0.f};
      if (kin) { xv = *(const float4*)(px[p] + gk); wv = *(const float4*)(pw[p] + gk); }
      const int ro = (sr + p * 32) * LDK + sc;
      split_f4(xv, &Xh[ro], &Xl[ro]);
      split_f4(wv, &Wh[ro], &Wl[ro]);
    }
    __syncthreads();

    bf16x8 ah[4], al[4], bh[4], bl[4];
#pragma unroll
    for (int mt = 0; mt < 4; mt++) {
      const int ro = (mb + mt * 16 + r16) * LDK + quad * 8;
      ah[mt] = *(const bf16x8*)&Xh[ro];
      al[mt] = *(const bf16x8*)&Xl[ro];
    }
#pragma unroll
    for (int nt = 0; nt < 4; nt++) {
      const int ro = (nb + nt * 16 + r16) * LDK + quad * 8;
      bh[nt] = *(const bf16x8*)&Wh[ro];
      bl[nt] = *(const bf16x8*)&Wl[ro];
    }
#pragma unroll
    for (int mt = 0; mt < 4; mt++)
#pragma unroll
      for (int nt = 0; nt < 4; nt++) {
        acc[mt][nt] = __builtin_amdgcn_mfma_f32_16x16x32_bf16(ah[mt], bh[nt], acc[mt][nt], 0, 0, 0);
        acc[mt][nt] = __builtin_amdgcn_mfma_f32_16x16x32_bf16(ah[mt], bl[nt], acc[mt][nt], 0, 0, 0);
        acc[mt][nt] = __builtin_amdgcn_mfma_f32_16x16x32_bf16(al[mt], bh[nt], acc[mt][nt], 0, 0, 0);
      }
    __syncthreads();
  }

  float bsum[4];
#pragma unroll
  for (int nt = 0; nt < 4; nt++) {
    const int col = n0 + nb + nt * 16 + r16;
    bsum[nt] = bias1[col] + bias2[col];
  }
#pragma unroll
  for (int mt = 0; mt < 4; mt++) {
    const int row = m0 + mb + mt * 16 + quad * 4;
#pragma unroll
    for (int nt = 0; nt < 4; nt++) {
      const int col = n0 + nb + nt * 16 + r16;
      float* Cp = C + (size_t)row * N + col;
#pragma unroll
      for (int reg = 0; reg < 4; reg++)
        Cp[(size_t)reg * N] = acc[mt][nt][reg] + bsum[nt];
    }
  }
}

// ---------------- attention score GEMM, split-bf16 MFMA, fused tanh*ctx ----------
__global__ __launch_bounds__(256, 2) void attn_gemm(
    const float* __restrict__ X, const float* __restrict__ W,
    const float* __restrict__ mlp_b, const float* __restrict__ ctx,
    float* __restrict__ scores, int M, int N, int K)
{
  __shared__ short Xh[128 * LDK], Xl[128 * LDK];
  __shared__ short Wh[128 * LDK], Wl[128 * LDK];
  const int tid = threadIdx.x;
  const int m0 = blockIdx.y * 128, n0 = blockIdx.x * 128;

  const int sr = tid >> 3;
  const int sc = (tid & 7) * 4;
  const float* px[4];
  const float* pw[4];
#pragma unroll
  for (int p = 0; p < 4; p++) {
    px[p] = X + (size_t)(m0 + sr + p * 32) * K;
    pw[p] = W + (size_t)(n0 + sr + p * 32) * K;
  }

  const int lane = tid & 63, w = tid >> 6;
  const int mb = (w & 1) * 64, nb = (w >> 1) * 64;
  const int r16 = lane & 15, quad = lane >> 4;

  f32x4 acc[4][4];
#pragma unroll
  for (int i = 0; i < 4; i++)
#pragma unroll
    for (int j = 0; j < 4; j++) acc[i][j] = (f32x4){0.f, 0.f, 0.f, 0.f};

  for (int k0 = 0; k0 < K; k0 += 32) {
    const int gk = k0 + sc;
#pragma unroll
    for (int p = 0; p < 4; p++) {
      float4 xv = *(const float4*)(px[p] + gk);
      float4 wv = *(const float4*)(pw[p] + gk);
      const int ro = (sr + p * 32) * LDK + sc;
      split_f4(xv, &Xh[ro], &Xl[ro]);
      split_f4(wv, &Wh[ro], &Wl[ro]);
    }
    __syncthreads();

    bf16x8 ah[4], al[4], bh[4], bl[4];
#pragma unroll
    for (int mt = 0; mt < 4; mt++) {
      const int ro = (mb + mt * 16 + r16) * LDK + quad * 8;
      ah[mt] = *(const bf16x8*)&Xh[ro];
      al[mt] = *(const bf16x8*)&Xl[ro];
    }
#pragma unroll
    for (int nt = 0; nt < 4; nt++) {
      const int ro = (nb + nt * 16 + r16) * LDK + quad * 8;
      bh[nt] = *(const bf16x8*)&Wh[ro];
      bl[nt] = *(const bf16x8*)&Wl[ro];
    }
#pragma unroll
    for (int mt = 0; mt < 4; mt++)
#pragma unroll
      for (int nt = 0; nt < 4; nt++) {
        acc[mt][nt] = __builtin_amdgcn_mfma_f32_16x16x32_bf16(ah[mt], bh[nt], acc[mt][nt], 0, 0, 0);
        acc[mt][nt] = __builtin_amdgcn_mfma_f32_16x16x32_bf16(ah[mt], bl[nt], acc[mt][nt], 0, 0, 0);
        acc[mt][nt] = __builtin_amdgcn_mfma_f32_16x16x32_bf16(al[mt], bh[nt], acc[mt][nt], 0, 0, 0);
      }
    __syncthreads();
  }

  float bb4[4], cc4[4];
#pragma unroll
  for (int nt = 0; nt < 4; nt++) {
    const int col = n0 + nb + nt * 16 + r16;
    bb4[nt] = mlp_b[col];
    cc4[nt] = ctx[col];
  }
#pragma unroll
  for (int mt = 0; mt < 4; mt++) {
#pragma unroll
    for (int reg = 0; reg < 4; reg++) {
      float ssum = 0.f;
#pragma unroll
      for (int nt = 0; nt < 4; nt++)
        ssum += tanhfast(acc[mt][nt][reg] + bb4[nt]) * cc4[nt];
      ssum += __shfl_xor(ssum, 1);
      ssum += __shfl_xor(ssum, 2);
      ssum += __shfl_xor(ssum, 4);
      ssum += __shfl_xor(ssum, 8);
      if (r16 == 0)
        atomicAdd(&scores[m0 + mb + mt * 16 + quad * 4 + reg], ssum);
    }
  }
}

// ---------------- LSTM recurrence chunk -- R16: R11 structure + flag exchange ----
// blocks: 256, blk = s*32 + d*16 + g (partners same (d,g), all s -> same XCD).
// Block owns dir d, batches g*8..g*8+7, hdims s*32..s*32+31.
// Exchange: producer stores 256 f32 h values -> __syncthreads (vmcnt drain) ->
// tid0 release-stores flags[slot][d][g][s]=1. Consumer polls flags[...][tid&7]
// (1 dword/thread/pass), barrier, then single bulk data read.
__global__ __launch_bounds__(256, 1) void lstm_rec(
    const float* __restrict__ xgF, const float* __restrict__ xgR,
    const float* __restrict__ whF, const float* __restrict__ whR,
    const int* __restrict__ lengths, float* __restrict__ hout,
    float* __restrict__ ring, float* __restrict__ bbuf, float* __restrict__ cbuf,
    int* __restrict__ flags, int t0)
{
  __shared__ short Ah[16 * LDA];   // h(t-1) hi-plane: rows 0-7 batches, 8-15 zero
  __shared__ short Al[16 * LDA];   // lo-plane
  __shared__ float gbuf[8 * 128];  // gate pre-acts: [b][gate*32 + hl]

  const int tid = threadIdx.x;
  const int blk = blockIdx.x;
  const int s = blk >> 5;
  const int d = (blk >> 4) & 1;
  const int g = blk & 15;
  const float* __restrict__ xg = d ? xgR : xgF;
  const float* __restrict__ wh = d ? whR : whF;

  const int lane = tid & 63;
  const int w = tid >> 6;              // wave index == gate index
  const int r16 = lane & 15, quad = lane >> 4;

  // cell / staging mapping: thread owns cell (b = g*8+cb, hdim = s*32+hl)
  const int cb = tid >> 5;             // 0..7
  const int hl = tid & 31;             // 0..31
  const int b = g * 8 + cb;
  const int hdim = s * 32 + hl;
  const int k0 = hl * 8;               // 0..248

  // ---- weight fragments (hi/lo bf16), once: 128 VGPR, statically indexed ----
  bf16x8 bh[2][8], bl[2][8];
#pragma unroll
  for (int nt = 0; nt < 2; nt++)
#pragma unroll
    for (int kt = 0; kt < 8; kt++) {
      const float* wr = wh + (size_t)(w * 256 + s * 32 + nt * 16 + r16) * 256
                           + kt * 32 + quad * 8;
      float4 v0 = *(const float4*)(wr);
      float4 v1 = *(const float4*)(wr + 4);
      split8(v0, v1, &bh[nt][kt], &bl[nt][kt]);
    }

  // ---- zero A pad rows 8..15 (stay zero all chunk) ----
  {
    int* za = (int*)(Ah + 8 * LDA);
    int* zb = (int*)(Al + 8 * LDA);
    for (int i = tid; i < (8 * LDA) / 2; i += 256) { za[i] = 0; zb[i] = 0; }
  }

  // ---- initial h(t0-1) and c ----
  float c;
  if (t0 == 0) {
    int* za = (int*)Ah;
    int* zb = (int*)Al;
    for (int i = tid; i < (8 * LDA) / 2; i += 256) { za[i] = 0; zb[i] = 0; }
    c = 0.f;
  } else {
    const float* src = bbuf + ((size_t)d * 128 + g * 8 + cb) * 256 + k0;
    float4 v0 = *(const float4*)src;
    float4 v1 = *(const float4*)(src + 4);
    bf16x8 hv, lv;
    split8(v0, v1, &hv, &lv);
    *(bf16x8*)&Ah[cb * LDA + k0] = hv;
    *(bf16x8*)&Al[cb * LDA + k0] = lv;
    c = cbuf[((size_t)d * 128 + b) * 256 + hdim];
  }
  int lb = lengths[b]; if (lb < 1) lb = 1;

  const float* xr0 = xg + (size_t)b * 1024 + hdim;
  float x0 = xr0[0], x1 = xr0[256], x2 = xr0[512], x3 = xr0[768];
  __syncthreads();

  const int tend = t0 + TC;
  for (int t = t0; t < tend; t++) {
    const int slot = t - t0;
    const bool last = (t == tend - 1);

    // ---- MFMA gate matvec: 48 MFMAs, 6 independent chains ----
    f32x4 aH0 = {0.f,0.f,0.f,0.f}, aM0 = {0.f,0.f,0.f,0.f}, aL0 = {0.f,0.f,0.f,0.f};
    f32x4 aH1 = {0.f,0.f,0.f,0.f}, aM1 = {0.f,0.f,0.f,0.f}, aL1 = {0.f,0.f,0.f,0.f};
#pragma unroll
    for (int kt = 0; kt < 8; kt++) {
      const int ro = r16 * LDA + kt * 32 + quad * 8;
      bf16x8 ahf = *(const bf16x8*)&Ah[ro];
      bf16x8 alf = *(const bf16x8*)&Al[ro];
      aH0 = MFMA16(ahf, bh[0][kt], aH0);
      aM0 = MFMA16(ahf, bl[0][kt], aM0);
      aL0 = MFMA16(alf, bh[0][kt], aL0);
      aH1 = MFMA16(ahf, bh[1][kt], aH1);
      aM1 = MFMA16(ahf, bl[1][kt], aM1);
      aL1 = MFMA16(alf, bh[1][kt], aL1);
    }
    // C layout: m = quad*4+reg (batch; valid m<8), n = r16 -> gbuf[b][w*32 + nt*16 + r16]
    if (quad < 2) {
#pragma unroll
      for (int reg = 0; reg < 4; reg++) {
        gbuf[(quad * 4 + reg) * 128 + w * 32 + r16]      = aH0[reg] + aM0[reg] + aL0[reg];
        gbuf[(quad * 4 + reg) * 128 + w * 32 + 16 + r16] = aH1[reg] + aM1[reg] + aL1[reg];
      }
    }
    __syncthreads();   // gbuf ready; Ah/Al reads complete -> safe to overwrite below

    // ---- cell update (thread owns (b, hdim)) ----
    const float gi = gbuf[cb * 128 +       hl] + x0;
    const float gf = gbuf[cb * 128 +  32 + hl] + x1;
    const float gg = gbuf[cb * 128 +  64 + hl] + x2;
    const float go = gbuf[cb * 128 +  96 + hl] + x3;
    const float si = sigf(gi), sf = sigf(gf);
    const float tg = tanhfast(gg), so = sigf(go);
    c = sf * c + si * tg;
    const float h = so * tanhfast(c);
    if (!last) {
      ATOM_ST(&ring[(((size_t)slot * 2 + d) * 128 + b) * 256 + hdim], h);
    } else {
      bbuf[((size_t)d * 128 + b) * 256 + hdim] = h;
    }
    const int tin = d ? ((t < lb) ? (lb - 1 - t) : t) : t;
    hout[((size_t)tin * 128 + b) * 512 + d * 256 + hdim] = h;

    if (!last) {
      // prefetch x(t+1)
      const float* xn = xg + ((size_t)(t + 1 - t0) * 128 + b) * 1024 + hdim;
      const float nx0 = xn[0], nx1 = xn[256], nx2 = xn[512], nx3 = xn[768];

      // ---- publish: drain data stores (barrier forces vmcnt(0)), then flag ----
      __syncthreads();
      const int fbase = ((slot * 2 + d) * 16 + g) * 8;
      if (tid == 0)
        __hip_atomic_store(&flags[fbase + s], 1,
                           __ATOMIC_RELEASE, __HIP_MEMORY_SCOPE_AGENT);

      // ---- consume: poll 8 flags (1 dword/thread/pass), then bulk read ----
      {
        int it = 0;
        for (;;) {
          const int v = ATOM_LD(&flags[fbase + (tid & 7)]);
          if (v != 0 || ++it >= 1000000) break;
        }
      }
      __syncthreads();   // all threads saw their flag -> all 8 producers done

      const float* su = ring + (((size_t)slot * 2 + d) * 128 + g * 8 + cb) * 256 + k0;
      float fv[8];
#pragma unroll
      for (int j = 0; j < 8; j++) fv[j] = ATOM_LD(&su[j]);
      float4 v0, v1;
      v0.x = fv[0]; v0.y = fv[1]; v0.z = fv[2]; v0.w = fv[3];
      v1.x = fv[4]; v1.y = fv[5]; v1.z = fv[6]; v1.w = fv[7];
      bf16x8 hv, lv;
      split8(v0, v1, &hv, &lv);
      *(bf16x8*)&Ah[cb * LDA + k0] = hv;
      *(bf16x8*)&Al[cb * LDA + k0] = lv;

      x0 = nx0; x1 = nx1; x2 = nx2; x3 = nx3;
      __syncthreads();   // A staged for step t+1
    }
  }
  cbuf[((size_t)d * 128 + b) * 256 + hdim] = c;
}

// ---------------- masked softmax over t + weighted sum ----------------
__global__ __launch_bounds__(256) void attn_final(
    const float* __restrict__ h2, const float* __restrict__ scores,
    const int* __restrict__ lengths, float* __restrict__ out)
{
  __shared__ float sl[256];
  __shared__ float red[256];
  const int b = blockIdx.x, tid = threadIdx.x;
  int lb = lengths[b]; if (lb < 1) lb = 1;
  const float sc = scores[(size_t)tid * 128 + b];
  const bool valid = (tid < lb);
  red[tid] = valid ? sc : -1e30f;
  __syncthreads();
  for (int off = 128; off > 0; off >>= 1) {
    if (tid < off) red[tid] = fmaxf(red[tid], red[tid + off]);
    __syncthreads();
  }
  const float mx = red[0];
  __syncthreads();
  const float p = valid ? __expf(sc - mx) : 0.f;
  red[tid] = p;
  __syncthreads();
  for (int off = 128; off > 0; off >>= 1) {
    if (tid < off) red[tid] += red[tid + off];
    __syncthreads();
  }
  const float inv = 1.f / red[0];
  __syncthreads();
  sl[tid] = p * inv;
  __syncthreads();

  float ax = 0.f, ay = 0.f;
  const int dd = tid * 2;
  for (int t = 0; t < 256; t++) {
    const float w = sl[t];
    if (w != 0.f) {
      const float* row = h2 + ((size_t)t * 128 + b) * 512 + dd;
      ax += w * row[0];
      ay += w * row[1];
    }
  }
  float2 r; r.x = ax; r.y = ay;
  *(float2*)(out + (size_t)b * 512 + dd) = r;
}

// ---------------- launch ----------------
extern "C" void kernel_launch(void* const* d_in, const int* in_sizes, int n_in,
                              void* d_out, int out_size, void* d_ws, size_t ws_size,
                              hipStream_t stream) {
  (void)in_sizes; (void)n_in; (void)out_size; (void)ws_size;
  const float* x        = (const float*)d_in[0];
  const int*   lengths  = (const int*)d_in[1];
  const float* w_ih_l0  = (const float*)d_in[2];
  const float* w_hh_l0  = (const float*)d_in[3];
  const float* b_ih_l0  = (const float*)d_in[4];
  const float* b_hh_l0  = (const float*)d_in[5];
  const float* w_ih_l0r = (const float*)d_in[6];
  const float* w_hh_l0r = (const float*)d_in[7];
  const float* b_ih_l0r = (const float*)d_in[8];
  const float* b_hh_l0r = (const float*)d_in[9];
  const float* w_ih_l1  = (const float*)d_in[10];
  const float* w_hh_l1  = (const float*)d_in[11];
  const float* b_ih_l1  = (const float*)d_in[12];
  const float* b_hh_l1  = (const float*)d_in[13];
  const float* w_ih_l1r = (const float*)d_in[14];
  const float* w_hh_l1r = (const float*)d_in[15];
  const float* b_ih_l1r = (const float*)d_in[16];
  const float* b_hh_l1r = (const float*)d_in[17];
  const float* mlp_w    = (const float*)d_in[18];
  const float* mlp_b    = (const float*)d_in[19];
  const float* ctx      = (const float*)d_in[20];
  float* out = (float*)d_out;

  // workspace layout (floats): ~219 MB
  float* ws = (float*)d_ws;
  const size_t XGC    = (size_t)TC * B_ * G4H;        // 8,388,608
  const size_t H_SZ   = (size_t)T_ * B_ * H2;         // 16,777,216
  const size_t RINGSZ = (size_t)TC * 2 * B_ * H_;     // 4,194,304 floats = 16 MB
  float* xgA    = ws;
  float* xgB    = xgA + XGC;
  float* h1     = xgB + XGC;
  float* h2     = h1 + H_SZ;
  float* ring   = h2 + H_SZ;
  float* bbuf   = ring + RINGSZ;                      // 65,536
  float* cbuf   = bbuf + 65536;                       // 65,536
  float* scores = cbuf + 65536;                       // 32,768
  int*   flags  = (int*)(scores + 32768);             // 16,384 ints = 64 KB

  (void)hipMemsetAsync(scores, 0, 32768 * 4, stream);

  dim3 blk(256);
  const dim3 pgrid(G4H / 128, TC, 2);   // (8, 64, 2 directions)

  // layer 0 (K=300), chunked over time
  for (int c = 0; c < T_ / TC; c++) {
    const int t0 = c * TC;
    proj_gemm2<<<pgrid, blk, 0, stream>>>(x, w_ih_l0, w_ih_l0r,
                                          b_ih_l0, b_hh_l0, b_ih_l0r, b_hh_l0r,
                                          xgA, xgB, G4H, D_, lengths, t0);
    (void)hipMemsetAsync(flags, 0, 16384 * 4, stream);
    lstm_rec<<<256, blk, 0, stream>>>(xgA, xgB, w_hh_l0, w_hh_l0r, lengths, h1,
                                      ring, bbuf, cbuf, flags, t0);
  }
  // layer 1 (K=512)
  for (int c = 0; c < T_ / TC; c++) {
    const int t0 = c * TC;
    proj_gemm2<<<pgrid, blk, 0, stream>>>(h1, w_ih_l1, w_ih_l1r,
                                          b_ih_l1, b_hh_l1, b_ih_l1r, b_hh_l1r,
                                          xgA, xgB, G4H, H2, lengths, t0);
    (void)hipMemsetAsync(flags, 0, 16384 * 4, stream);
    lstm_rec<<<256, blk, 0, stream>>>(xgA, xgB, w_hh_l1, w_hh_l1r, lengths, h2,
                                      ring, bbuf, cbuf, flags, t0);
  }
  // attention (M=32768, N=512, K=512)
  attn_gemm<<<dim3(H2 / 128, (T_ * B_) / 128), blk, 0, stream>>>(h2, mlp_w, mlp_b, ctx, scores, T_ * B_, H2, H2);
  attn_final<<<B_, blk, 0, stream>>>(h2, scores, lengths, out);
}

// Round 8
// 2639.103 us; speedup vs baseline: 1.7671x; 1.7671x over previous
//
#include <hip/hip_runtime.h>

// SentenceEncodingRNN2: 2-layer BiLSTM (T=256,B=128,D=300,H=256) + attention pooling.
// Round 17: fuse proj into lstm dead time. R16 post-mortem: flag protocol added a
//   serial L3 round trip (483us) -- R11's direct sentinel poll is the best exchange;
//   frozen. New structure: ONE 256-step lstm dispatch per layer (R11 block layout,
//   no chunking/bbuf/cbuf) that ALSO computes next-steps' input projections in the
//   ~75% idle time per step (1 proj k-iter of a 128x128 tile between ring store and
//   poll). Block (s,d,g) owns proj tiles n=s*128, dir=d, y=64+16w+g (w=0..11).
//   xg = 76-slot ring (overwrite margin >=13 steps); h-exchange ring = 4 slots with
//   epoch parity bit in lo-bf16 LSB (ABA-safe, +-2^-16 noise); packed u32 exchange.
//   Standalone proj only for y=0..63 per layer. ws = 215.1MB (prev session: 218.8).
//   attn_gemm / attn_final unchanged.

#define T_ 256
#define B_ 128
#define D_ 300
#define H_ 256
#define G4H 1024   // 4*H
#define H2 512     // 2*H
#define LDK 40     // proj/attn LDS k-stride in bf16 (80 B rows)
#define LDA 264    // lstm A-tile LDS k-stride in bf16 (256+8)
#define XGS 76     // xg ring slots
#define RSLOTS 4   // h-exchange ring slots

typedef __attribute__((ext_vector_type(8))) short bf16x8;
typedef __attribute__((ext_vector_type(4))) short short4v;
typedef __attribute__((ext_vector_type(4))) float f32x4;

#define MFMA16(a, b, c) __builtin_amdgcn_mfma_f32_16x16x32_bf16(a, b, c, 0, 0, 0)
#define ATOM_ST(p, v) __hip_atomic_store((p), (v), __ATOMIC_RELAXED, __HIP_MEMORY_SCOPE_AGENT)
#define ATOM_LD(p) __hip_atomic_load((p), __ATOMIC_RELAXED, __HIP_MEMORY_SCOPE_AGENT)

// ---------------- helpers ----------------
__device__ __forceinline__ float sigf(float x) { return 1.f / (1.f + __expf(-x)); }
__device__ __forceinline__ float tanhfast(float x) { return 2.f / (1.f + __expf(-2.f * x)) - 1.f; }

__device__ __forceinline__ short hi_bf16(float x) {
  return (short)(__float_as_uint(x) >> 16);
}
__device__ __forceinline__ short lo_bf16(float x) {
  float lo = x - __uint_as_float(__float_as_uint(x) & 0xFFFF0000u);
  return (short)(__float_as_uint(lo) >> 16);
}

__device__ __forceinline__ void split_f4(const float4 v, short* hp, short* lp) {
  short4v h, l;
  h.x = hi_bf16(v.x); l.x = lo_bf16(v.x);
  h.y = hi_bf16(v.y); l.y = lo_bf16(v.y);
  h.z = hi_bf16(v.z); l.z = lo_bf16(v.z);
  h.w = hi_bf16(v.w); l.w = lo_bf16(v.w);
  *(short4v*)hp = h;
  *(short4v*)lp = l;
}

__device__ __forceinline__ void split8(const float4 v0, const float4 v1,
                                       bf16x8* hp, bf16x8* lp) {
  bf16x8 h, l;
  h[0] = hi_bf16(v0.x); l[0] = lo_bf16(v0.x);
  h[1] = hi_bf16(v0.y); l[1] = lo_bf16(v0.y);
  h[2] = hi_bf16(v0.z); l[2] = lo_bf16(v0.z);
  h[3] = hi_bf16(v0.w); l[3] = lo_bf16(v0.w);
  h[4] = hi_bf16(v1.x); l[4] = lo_bf16(v1.x);
  h[5] = hi_bf16(v1.y); l[5] = lo_bf16(v1.y);
  h[6] = hi_bf16(v1.z); l[6] = lo_bf16(v1.z);
  h[7] = hi_bf16(v1.w); l[7] = lo_bf16(v1.w);
  *hp = h; *lp = l;
}

// ---------------- dual-direction projection GEMM (standalone, y=0..63) -----------
__global__ __launch_bounds__(256, 2) void proj_gemm2(
    const float* __restrict__ X,
    const float* __restrict__ W0, const float* __restrict__ W1,
    const float* __restrict__ b1f, const float* __restrict__ b2f,
    const float* __restrict__ b1r, const float* __restrict__ b2r,
    float* __restrict__ C0, float* __restrict__ C1,
    int N, int K, const int* __restrict__ lengths, int t0)
{
  __shared__ short Xh[128 * LDK], Xl[128 * LDK];
  __shared__ short Wh[128 * LDK], Wl[128 * LDK];
  const int rev = blockIdx.z;
  const float* __restrict__ W = rev ? W1 : W0;
  const float* __restrict__ bias1 = rev ? b1r : b1f;
  const float* __restrict__ bias2 = rev ? b2r : b2f;
  float* __restrict__ C = rev ? C1 : C0;

  const int tid = threadIdx.x;
  const int m0 = blockIdx.y * 128, n0 = blockIdx.x * 128;
  const int s_step = t0 + blockIdx.y;

  const int sr = tid >> 3;
  const int sc = (tid & 7) * 4;
  const float* px[4];
  const float* pw[4];
#pragma unroll
  for (int p = 0; p < 4; p++) {
    const int r = sr + p * 32;          // r == batch index within tile
    int ss = s_step;
    if (rev) {
      int lb = lengths[r]; if (lb < 1) lb = 1;
      ss = (s_step < lb) ? (lb - 1 - s_step) : s_step;
    }
    px[p] = X + (size_t)(ss * 128 + r) * K;
    pw[p] = W + (size_t)(n0 + r) * K;
  }

  const int lane = tid & 63, w = tid >> 6;
  const int mb = (w & 1) * 64, nb = (w >> 1) * 64;
  const int r16 = lane & 15, quad = lane >> 4;

  f32x4 acc[4][4];
#pragma unroll
  for (int i = 0; i < 4; i++)
#pragma unroll
    for (int j = 0; j < 4; j++) acc[i][j] = (f32x4){0.f, 0.f, 0.f, 0.f};

  for (int k0 = 0; k0 < K; k0 += 32) {
    const int gk = k0 + sc;
    const bool kin = (gk < K);          // K % 4 == 0 -> whole float4 in/out
#pragma unroll
    for (int p = 0; p < 4; p++) {
      float4 xv = {0.f, 0.f, 0.f, 0.f}, wv = {0.f, 0.f, 0.f, 0.f};
      if (kin) { xv = *(const float4*)(px[p] + gk); wv = *(const float4*)(pw[p] + gk); }
      const int ro = (sr + p * 32) * LDK + sc;
      split_f4(xv, &Xh[ro], &Xl[ro]);
      split_f4(wv, &Wh[ro], &Wl[ro]);
    }
    __syncthreads();

    bf16x8 ah[4], al[4], bh[4], bl[4];
#pragma unroll
    for (int mt = 0; mt < 4; mt++) {
      const int ro = (mb + mt * 16 + r16) * LDK + quad * 8;
      ah[mt] = *(const bf16x8*)&Xh[ro];
      al[mt] = *(const bf16x8*)&Xl[ro];
    }
#pragma unroll
    for (int nt = 0; nt < 4; nt++) {
      const int ro = (nb + nt * 16 + r16) * LDK + quad * 8;
      bh[nt] = *(const bf16x8*)&Wh[ro];
      bl[nt] = *(const bf16x8*)&Wl[ro];
    }
#pragma unroll
    for (int mt = 0; mt < 4; mt++)
#pragma unroll
      for (int nt = 0; nt < 4; nt++) {
        acc[mt][nt] = __builtin_amdgcn_mfma_f32_16x16x32_bf16(ah[mt], bh[nt], acc[mt][nt], 0, 0, 0);
        acc[mt][nt] = __builtin_amdgcn_mfma_f32_16x16x32_bf16(ah[mt], bl[nt], acc[mt][nt], 0, 0, 0);
        acc[mt][nt] = __builtin_amdgcn_mfma_f32_16x16x32_bf16(al[mt], bh[nt], acc[mt][nt], 0, 0, 0);
      }
    __syncthreads();
  }

  float bsum[4];
#pragma unroll
  for (int nt = 0; nt < 4; nt++) {
    const int col = n0 + nb + nt * 16 + r16;
    bsum[nt] = bias1[col] + bias2[col];
  }
#pragma unroll
  for (int mt = 0; mt < 4; mt++) {
    const int row = m0 + mb + mt * 16 + quad * 4;
#pragma unroll
    for (int nt = 0; nt < 4; nt++) {
      const int col = n0 + nb + nt * 16 + r16;
      float* Cp = C + (size_t)row * N + col;
#pragma unroll
      for (int reg = 0; reg < 4; reg++)
        Cp[(size_t)reg * N] = acc[mt][nt][reg] + bsum[nt];
    }
  }
}

// ---------------- attention score GEMM, split-bf16 MFMA, fused tanh*ctx ----------
__global__ __launch_bounds__(256, 2) void attn_gemm(
    const float* __restrict__ X, const float* __restrict__ W,
    const float* __restrict__ mlp_b, const float* __restrict__ ctx,
    float* __restrict__ scores, int M, int N, int K)
{
  __shared__ short Xh[128 * LDK], Xl[128 * LDK];
  __shared__ short Wh[128 * LDK], Wl[128 * LDK];
  const int tid = threadIdx.x;
  const int m0 = blockIdx.y * 128, n0 = blockIdx.x * 128;

  const int sr = tid >> 3;
  const int sc = (tid & 7) * 4;
  const float* px[4];
  const float* pw[4];
#pragma unroll
  for (int p = 0; p < 4; p++) {
    px[p] = X + (size_t)(m0 + sr + p * 32) * K;
    pw[p] = W + (size_t)(n0 + sr + p * 32) * K;
  }

  const int lane = tid & 63, w = tid >> 6;
  const int mb = (w & 1) * 64, nb = (w >> 1) * 64;
  const int r16 = lane & 15, quad = lane >> 4;

  f32x4 acc[4][4];
#pragma unroll
  for (int i = 0; i < 4; i++)
#pragma unroll
    for (int j = 0; j < 4; j++) acc[i][j] = (f32x4){0.f, 0.f, 0.f, 0.f};

  for (int k0 = 0; k0 < K; k0 += 32) {
    const int gk = k0 + sc;
#pragma unroll
    for (int p = 0; p < 4; p++) {
      float4 xv = *(const float4*)(px[p] + gk);
      float4 wv = *(const float4*)(pw[p] + gk);
      const int ro = (sr + p * 32) * LDK + sc;
      split_f4(xv, &Xh[ro], &Xl[ro]);
      split_f4(wv, &Wh[ro], &Wl[ro]);
    }
    __syncthreads();

    bf16x8 ah[4], al[4], bh[4], bl[4];
#pragma unroll
    for (int mt = 0; mt < 4; mt++) {
      const int ro = (mb + mt * 16 + r16) * LDK + quad * 8;
      ah[mt] = *(const bf16x8*)&Xh[ro];
      al[mt] = *(const bf16x8*)&Xl[ro];
    }
#pragma unroll
    for (int nt = 0; nt < 4; nt++) {
      const int ro = (nb + nt * 16 + r16) * LDK + quad * 8;
      bh[nt] = *(const bf16x8*)&Wh[ro];
      bl[nt] = *(const bf16x8*)&Wl[ro];
    }
#pragma unroll
    for (int mt = 0; mt < 4; mt++)
#pragma unroll
      for (int nt = 0; nt < 4; nt++) {
        acc[mt][nt] = __builtin_amdgcn_mfma_f32_16x16x32_bf16(ah[mt], bh[nt], acc[mt][nt], 0, 0, 0);
        acc[mt][nt] = __builtin_amdgcn_mfma_f32_16x16x32_bf16(ah[mt], bl[nt], acc[mt][nt], 0, 0, 0);
        acc[mt][nt] = __builtin_amdgcn_mfma_f32_16x16x32_bf16(al[mt], bh[nt], acc[mt][nt], 0, 0, 0);
      }
    __syncthreads();
  }

  float bb4[4], cc4[4];
#pragma unroll
  for (int nt = 0; nt < 4; nt++) {
    const int col = n0 + nb + nt * 16 + r16;
    bb4[nt] = mlp_b[col];
    cc4[nt] = ctx[col];
  }
#pragma unroll
  for (int mt = 0; mt < 4; mt++) {
#pragma unroll
    for (int reg = 0; reg < 4; reg++) {
      float ssum = 0.f;
#pragma unroll
      for (int nt = 0; nt < 4; nt++)
        ssum += tanhfast(acc[mt][nt][reg] + bb4[nt]) * cc4[nt];
      ssum += __shfl_xor(ssum, 1);
      ssum += __shfl_xor(ssum, 2);
      ssum += __shfl_xor(ssum, 4);
      ssum += __shfl_xor(ssum, 8);
      if (r16 == 0)
        atomicAdd(&scores[m0 + mb + mt * 16 + quad * 4 + reg], ssum);
    }
  }
}

// ---------------- fused LSTM recurrence + in-flight proj -- R17 ------------------
// 256 blocks, blk = s*32 + d*16 + g (R11 layout; partners same (d,g), all s -> XCD).
// lstm: R11 protocol, 256 steps, packed-u32 ring (4 slots, epoch parity in lo LSB).
// proj: block owns tiles (n0=s*128, dir=d, y=64+16*wj+g, wj=0..11); one k-iter per
//   step (steps 0..191), epilogue at step 16*wj+15 into xg slot y%76 (margin >=13).
__global__ __launch_bounds__(256, 1) void lstm_fused(
    float* __restrict__ xgF, float* __restrict__ xgR,
    const float* __restrict__ XSRC,
    const float* __restrict__ whF, const float* __restrict__ whR,
    const float* __restrict__ wihF, const float* __restrict__ wihR,
    const float* __restrict__ b1f, const float* __restrict__ b2f,
    const float* __restrict__ b1r, const float* __restrict__ b2r,
    const int* __restrict__ lengths, float* __restrict__ hout,
    float* __restrict__ ring, int K)
{
  __shared__ short Ah[16 * LDA], Al[16 * LDA];   // rows 0-7 batches, 8-15 zero
  __shared__ float gbuf[8 * 128];
  __shared__ short PXh[128 * LDK], PXl[128 * LDK];
  __shared__ short PWh[128 * LDK], PWl[128 * LDK];

  const int tid = threadIdx.x;
  const int blk = blockIdx.x;
  const int s = blk >> 5;
  const int d = (blk >> 4) & 1;
  const int g = blk & 15;
  float* __restrict__ xgd = d ? xgR : xgF;
  const float* __restrict__ wh = d ? whR : whF;
  const float* __restrict__ wih = d ? wihR : wihF;
  const float* __restrict__ bias1 = d ? b1r : b1f;
  const float* __restrict__ bias2 = d ? b2r : b2f;
  unsigned* __restrict__ ring32 = (unsigned*)ring;

  const int lane = tid & 63;
  const int w = tid >> 6;              // wave index == lstm gate index
  const int r16 = lane & 15, quad = lane >> 4;

  // lstm cell/staging mapping
  const int cb = tid >> 5;             // 0..7
  const int hl = tid & 31;             // 0..31
  const int b = g * 8 + cb;
  const int hdim = s * 32 + hl;
  const int k0 = hl * 8;               // 0..248

  // proj mappings
  const int sr = tid >> 3;             // staging row 0..31
  const int sc = (tid & 7) * 4;        // staging col
  const int mb = (w & 1) * 64, nb = (w >> 1) * 64;
  const int n0 = s * 128;
  const int KITERS = (K + 31) >> 5;

  // ---- lstm weight fragments (hi/lo bf16): 128 VGPR, statically indexed ----
  bf16x8 bh[2][8], bl[2][8];
#pragma unroll
  for (int nt = 0; nt < 2; nt++)
#pragma unroll
    for (int kt = 0; kt < 8; kt++) {
      const float* wr = wh + (size_t)(w * 256 + s * 32 + nt * 16 + r16) * 256
                           + kt * 32 + quad * 8;
      float4 v0 = *(const float4*)(wr);
      float4 v1 = *(const float4*)(wr + 4);
      split8(v0, v1, &bh[nt][kt], &bl[nt][kt]);
    }

  // ---- proj accumulators ----
  f32x4 pacc[4][4];
#pragma unroll
  for (int i = 0; i < 4; i++)
#pragma unroll
    for (int j = 0; j < 4; j++) pacc[i][j] = (f32x4){0.f, 0.f, 0.f, 0.f};

  // ---- init: zero A (h(-1)=0 + pad rows), c=0, lengths, x(0) ----
  {
    int* za = (int*)Ah;
    int* zb = (int*)Al;
    for (int i = tid; i < (16 * LDA) / 2; i += 256) { za[i] = 0; zb[i] = 0; }
  }
  float c = 0.f;
  int lb = lengths[b]; if (lb < 1) lb = 1;
  const float* xr0 = xgd + (size_t)b * 1024 + hdim;
  float x0 = ATOM_LD(xr0), x1 = ATOM_LD(xr0 + 256);
  float x2 = ATOM_LD(xr0 + 512), x3 = ATOM_LD(xr0 + 768);
  __syncthreads();

  for (int t = 0; t < T_; t++) {
    const bool last = (t == T_ - 1);

    // ---- lstm MFMA gate matvec: 48 MFMAs, 6 independent chains ----
    f32x4 aH0 = {0.f,0.f,0.f,0.f}, aM0 = {0.f,0.f,0.f,0.f}, aL0 = {0.f,0.f,0.f,0.f};
    f32x4 aH1 = {0.f,0.f,0.f,0.f}, aM1 = {0.f,0.f,0.f,0.f}, aL1 = {0.f,0.f,0.f,0.f};
#pragma unroll
    for (int kt = 0; kt < 8; kt++) {
      const int ro = r16 * LDA + kt * 32 + quad * 8;
      bf16x8 ahf = *(const bf16x8*)&Ah[ro];
      bf16x8 alf = *(const bf16x8*)&Al[ro];
      aH0 = MFMA16(ahf, bh[0][kt], aH0);
      aM0 = MFMA16(ahf, bl[0][kt], aM0);
      aL0 = MFMA16(alf, bh[0][kt], aL0);
      aH1 = MFMA16(ahf, bh[1][kt], aH1);
      aM1 = MFMA16(ahf, bl[1][kt], aM1);
      aL1 = MFMA16(alf, bh[1][kt], aL1);
    }
    if (quad < 2) {
#pragma unroll
      for (int reg = 0; reg < 4; reg++) {
        gbuf[(quad * 4 + reg) * 128 + w * 32 + r16]      = aH0[reg] + aM0[reg] + aL0[reg];
        gbuf[(quad * 4 + reg) * 128 + w * 32 + 16 + r16] = aH1[reg] + aM1[reg] + aL1[reg];
      }
    }
    __syncthreads();   // gbuf ready; Ah/Al reads complete

    // ---- cell update ----
    const float gi = gbuf[cb * 128 +       hl] + x0;
    const float gf = gbuf[cb * 128 +  32 + hl] + x1;
    const float gg = gbuf[cb * 128 +  64 + hl] + x2;
    const float go = gbuf[cb * 128 +  96 + hl] + x3;
    const float si = sigf(gi), sf = sigf(gf);
    const float tg = tanhfast(gg), so = sigf(go);
    c = sf * c + si * tg;
    const float h = so * tanhfast(c);
    if (!last) {
      const unsigned hu = (unsigned)(unsigned short)hi_bf16(h);
      const unsigned lu = (unsigned)(unsigned short)lo_bf16(h);
      const unsigned pv = (hu << 16) | (lu & 0xFFFEu) | (unsigned)((t >> 2) & 1);
      ATOM_ST(&ring32[(((t & 3) * 2 + d) * 128 + b) * 256 + hdim], pv);
    }
    const int tin = d ? ((t < lb) ? (lb - 1 - t) : t) : t;
    hout[((size_t)tin * 128 + b) * 512 + d * 256 + hdim] = h;

    // ---- fused proj: one k-iter of tile (n0, dir=d, y=64+16*wj+g) ----
    if (t < 192) {
      const int wj = t >> 4, ki = t & 15;
      const int y = 64 + wj * 16 + g;
      if (ki < KITERS) {
        const int gk = ki * 32 + sc;
        const bool kin = (gk < K);
#pragma unroll
        for (int p = 0; p < 4; p++) {
          const int r = sr + p * 32;
          float4 xv = {0.f, 0.f, 0.f, 0.f}, wv = {0.f, 0.f, 0.f, 0.f};
          if (kin) {
            int ss = y;
            if (d) {
              int lbr = lengths[r]; if (lbr < 1) lbr = 1;
              ss = (y < lbr) ? (lbr - 1 - y) : y;
            }
            xv = *(const float4*)(XSRC + ((size_t)ss * 128 + r) * K + gk);
            wv = *(const float4*)(wih + (size_t)(n0 + r) * K + gk);
          }
          const int ro = (sr + p * 32) * LDK + sc;
          split_f4(xv, &PXh[ro], &PXl[ro]);
          split_f4(wv, &PWh[ro], &PWl[ro]);
        }
        __syncthreads();

        bf16x8 pah[4], pal[4], pbh[4], pbl[4];
#pragma unroll
        for (int mt = 0; mt < 4; mt++) {
          const int ro = (mb + mt * 16 + r16) * LDK + quad * 8;
          pah[mt] = *(const bf16x8*)&PXh[ro];
          pal[mt] = *(const bf16x8*)&PXl[ro];
        }
#pragma unroll
        for (int nt = 0; nt < 4; nt++) {
          const int ro = (nb + nt * 16 + r16) * LDK + quad * 8;
          pbh[nt] = *(const bf16x8*)&PWh[ro];
          pbl[nt] = *(const bf16x8*)&PWl[ro];
        }
#pragma unroll
        for (int mt = 0; mt < 4; mt++)
#pragma unroll
          for (int nt = 0; nt < 4; nt++) {
            pacc[mt][nt] = MFMA16(pah[mt], pbh[nt], pacc[mt][nt]);
            pacc[mt][nt] = MFMA16(pah[mt], pbl[nt], pacc[mt][nt]);
            pacc[mt][nt] = MFMA16(pal[mt], pbh[nt], pacc[mt][nt]);
          }
      }
      if (ki == 15) {
        const int yslot = y % XGS;
        float bsum[4];
#pragma unroll
        for (int nt = 0; nt < 4; nt++) {
          const int col = n0 + nb + nt * 16 + r16;
          bsum[nt] = bias1[col] + bias2[col];
        }
#pragma unroll
        for (int mt = 0; mt < 4; mt++) {
          const int row = mb + mt * 16 + quad * 4;
#pragma unroll
          for (int nt = 0; nt < 4; nt++) {
            const int col = n0 + nb + nt * 16 + r16;
            float* Cp = xgd + ((size_t)yslot * 128 + row) * 1024 + col;
#pragma unroll
            for (int reg = 0; reg < 4; reg++)
              ATOM_ST(&Cp[(size_t)reg * 1024], pacc[mt][nt][reg] + bsum[nt]);
            pacc[mt][nt] = (f32x4){0.f, 0.f, 0.f, 0.f};
          }
        }
      }
    }

    // ---- prefetch x(t+1), spin on ring (direct data poll, parity check) ----
    if (!last) {
      const int ns = (t + 1) % XGS;
      const float* xn = xgd + ((size_t)ns * 128 + b) * 1024 + hdim;
      const float nx0 = ATOM_LD(xn), nx1 = ATOM_LD(xn + 256);
      const float nx2 = ATOM_LD(xn + 512), nx3 = ATOM_LD(xn + 768);

      const unsigned* ru = ring32 + (((t & 3) * 2 + d) * 128 + g * 8 + cb) * 256 + k0;
      const unsigned par = (unsigned)((t >> 2) & 1);
      unsigned uv[8];
      int it = 0;
      for (;;) {
        bool ok = true;
#pragma unroll
        for (int j = 0; j < 8; j++) {
          uv[j] = ATOM_LD(&ru[j]);
          ok &= ((uv[j] & 1u) == par);
        }
        if (ok || ++it >= 100000) break;
      }
      bf16x8 hv, lv;
#pragma unroll
      for (int j = 0; j < 8; j++) {
        hv[j] = (short)(uv[j] >> 16);
        lv[j] = (short)(uv[j] & 0xFFFFu);
      }
      *(bf16x8*)&Ah[cb * LDA + k0] = hv;
      *(bf16x8*)&Al[cb * LDA + k0] = lv;

      x0 = nx0; x1 = nx1; x2 = nx2; x3 = nx3;
      __syncthreads();   // A + PX staged/consumed ordering for step t+1
    }
  }
}

// ---------------- masked softmax over t + weighted sum ----------------
__global__ __launch_bounds__(256) void attn_final(
    const float* __restrict__ h2, const float* __restrict__ scores,
    const int* __restrict__ lengths, float* __restrict__ out)
{
  __shared__ float sl[256];
  __shared__ float red[256];
  const int b = blockIdx.x, tid = threadIdx.x;
  int lb = lengths[b]; if (lb < 1) lb = 1;
  const float sc = scores[(size_t)tid * 128 + b];
  const bool valid = (tid < lb);
  red[tid] = valid ? sc : -1e30f;
  __syncthreads();
  for (int off = 128; off > 0; off >>= 1) {
    if (tid < off) red[tid] = fmaxf(red[tid], red[tid + off]);
    __syncthreads();
  }
  const float mx = red[0];
  __syncthreads();
  const float p = valid ? __expf(sc - mx) : 0.f;
  red[tid] = p;
  __syncthreads();
  for (int off = 128; off > 0; off >>= 1) {
    if (tid < off) red[tid] += red[tid + off];
    __syncthreads();
  }
  const float inv = 1.f / red[0];
  __syncthreads();
  sl[tid] = p * inv;
  __syncthreads();

  float ax = 0.f, ay = 0.f;
  const int dd = tid * 2;
  for (int t = 0; t < 256; t++) {
    const float w = sl[t];
    if (w != 0.f) {
      const float* row = h2 + ((size_t)t * 128 + b) * 512 + dd;
      ax += w * row[0];
      ay += w * row[1];
    }
  }
  float2 r; r.x = ax; r.y = ay;
  *(float2*)(out + (size_t)b * 512 + dd) = r;
}

// ---------------- launch ----------------
extern "C" void kernel_launch(void* const* d_in, const int* in_sizes, int n_in,
                              void* d_out, int out_size, void* d_ws, size_t ws_size,
                              hipStream_t stream) {
  (void)in_sizes; (void)n_in; (void)out_size; (void)ws_size;
  const float* x        = (const float*)d_in[0];
  const int*   lengths  = (const int*)d_in[1];
  const float* w_ih_l0  = (const float*)d_in[2];
  const float* w_hh_l0  = (const float*)d_in[3];
  const float* b_ih_l0  = (const float*)d_in[4];
  const float* b_hh_l0  = (const float*)d_in[5];
  const float* w_ih_l0r = (const float*)d_in[6];
  const float* w_hh_l0r = (const float*)d_in[7];
  const float* b_ih_l0r = (const float*)d_in[8];
  const float* b_hh_l0r = (const float*)d_in[9];
  const float* w_ih_l1  = (const float*)d_in[10];
  const float* w_hh_l1  = (const float*)d_in[11];
  const float* b_ih_l1  = (const float*)d_in[12];
  const float* b_hh_l1  = (const float*)d_in[13];
  const float* w_ih_l1r = (const float*)d_in[14];
  const float* w_hh_l1r = (const float*)d_in[15];
  const float* b_ih_l1r = (const float*)d_in[16];
  const float* b_hh_l1r = (const float*)d_in[17];
  const float* mlp_w    = (const float*)d_in[18];
  const float* mlp_b    = (const float*)d_in[19];
  const float* ctx      = (const float*)d_in[20];
  float* out = (float*)d_out;

  // workspace layout (floats): 215.1 MB (prev session used 218.8)
  float* ws = (float*)d_ws;
  const size_t XG76  = (size_t)XGS * B_ * G4H;        // 9,961,472
  const size_t H_SZ  = (size_t)T_ * B_ * H2;          // 16,777,216
  const size_t RINGF = (size_t)RSLOTS * 2 * B_ * H_;  // 262,144
  float* xgF    = ws;
  float* xgR    = xgF + XG76;
  float* h1     = xgR + XG76;
  float* h2     = h1 + H_SZ;
  float* ring   = h2 + H_SZ;
  float* scores = ring + RINGF;                       // 32,768

  (void)hipMemsetAsync(scores, 0, 32768 * 4, stream);

  dim3 blk(256);
  const dim3 pgrid(G4H / 128, 64, 2);   // standalone proj: y = 0..63, both dirs

  // ---- layer 0 ----
  proj_gemm2<<<pgrid, blk, 0, stream>>>(x, w_ih_l0, w_ih_l0r,
                                        b_ih_l0, b_hh_l0, b_ih_l0r, b_hh_l0r,
                                        xgF, xgR, G4H, D_, lengths, 0);
  (void)hipMemsetAsync(ring, 0xFF, RINGF * 4, stream);   // sentinel (parity=1)
  lstm_fused<<<256, blk, 0, stream>>>(xgF, xgR, x, w_hh_l0, w_hh_l0r,
                                      w_ih_l0, w_ih_l0r,
                                      b_ih_l0, b_hh_l0, b_ih_l0r, b_hh_l0r,
                                      lengths, h1, ring, D_);
  // ---- layer 1 ----
  proj_gemm2<<<pgrid, blk, 0, stream>>>(h1, w_ih_l1, w_ih_l1r,
                                        b_ih_l1, b_hh_l1, b_ih_l1r, b_hh_l1r,
                                        xgF, xgR, G4H, H2, lengths, 0);
  (void)hipMemsetAsync(ring, 0xFF, RINGF * 4, stream);
  lstm_fused<<<256, blk, 0, stream>>>(xgF, xgR, h1, w_hh_l1, w_hh_l1r,
                                      w_ih_l1, w_ih_l1r,
                                      b_ih_l1, b_hh_l1, b_ih_l1r, b_hh_l1r,
                                      lengths, h2, ring, H2);
  // ---- attention ----
  attn_gemm<<<dim3(H2 / 128, (T_ * B_) / 128), blk, 0, stream>>>(h2, mlp_w, mlp_b, ctx, scores, T_ * B_, H2, H2);
  attn_final<<<B_, blk, 0, stream>>>(h2, scores, lengths, out);
}